// Round 9
// baseline (456.866 us; speedup 1.0000x reference)
//
#include <hip/hip_runtime.h>
#include <stdint.h>

#define N_NODES 50000
#define N_EDGES 1600000
#define F_IN    264
#define F_HID   48
#define F_CAT   144
#define F_MID   64
#define K_PAD   288   // 264 padded up to multiple of 32
#define K_MLP   160   // 144 padded up to multiple of 32
#define GEMM_BLOCKS 391          // ceil(50000/128)
#define EPASS_BLOCKS 6250        // 1600000/256 exactly

typedef unsigned short u16;
typedef unsigned int   u32;

using short8  = __attribute__((ext_vector_type(8))) short;
using floatx4 = __attribute__((ext_vector_type(4))) float;

__device__ __forceinline__ float bf2f(u16 u) {
    return __uint_as_float(((u32)u) << 16);
}
__device__ __forceinline__ u16 f2bf(float f) {
    u32 u = __float_as_uint(f);
    u32 r = (u + 0x7fffu + ((u >> 16) & 1u)) >> 16;   // round-nearest-even
    return (u16)r;
}
__device__ __forceinline__ float ldf(const void* p, size_t i, int isbf) {
    return isbf ? bf2f(((const u16*)p)[i]) : ((const float*)p)[i];
}
__device__ __forceinline__ floatx4 max4(floatx4 a, floatx4 b) {
    floatx4 r;
    r[0] = fmaxf(a[0], b[0]); r[1] = fmaxf(a[1], b[1]);
    r[2] = fmaxf(a[2], b[2]); r[3] = fmaxf(a[3], b[3]);
    return r;
}

// ---------- inline dtype probes (uniform 128B broadcast reads, no flags pass)
// bf16 storage: even u16s of x are genuine bf16 (exponent in [90,140] or 0).
// fp32 storage: even u16s are mantissa halves -> ~10% "sane" rate.
__device__ __forceinline__ int probe_isbf(const u16* __restrict__ xu) {
    int sane = 0;
#pragma unroll
    for (int i = 0; i < 32; ++i) {
        u16 h = xu[2 * i];
        u32 E = (h >> 7) & 0xFF;
        sane += (h == 0 || (E >= 90 && E <= 140)) ? 1 : 0;
    }
    return sane >= 24;
}
// int64 storage: odd words (high halves) of edge_index are all zero.
__device__ __forceinline__ int probe_is64(const int* __restrict__ ei) {
    int nz = 0;
#pragma unroll
    for (int i = 0; i < 16; ++i) nz |= ei[2 * i + 1];
    return nz == 0;
}

__device__ __forceinline__ int ld_row(const int* ei, int e, int is64) {
    return is64 ? ei[2 * (size_t)e] : ei[e];
}
__device__ __forceinline__ int ld_col(const int* ei, int e, int is64) {
    return is64 ? ei[2 * ((size_t)N_EDGES + e)] : ei[(size_t)N_EDGES + e];
}

// ---------- prep: Wt + W1bt bf16 staging + fp32 conversion of small params ---
__global__ __launch_bounds__(256)
void k_prep(const void* __restrict__ x,
            const void* __restrict__ WM, const void* __restrict__ WA,
            const void* __restrict__ WS, const void* __restrict__ W1,
            const void* __restrict__ bM, const void* __restrict__ bA,
            const void* __restrict__ b1, const void* __restrict__ W2,
            const void* __restrict__ b2,
            u16* __restrict__ Wt, u16* __restrict__ W1bt,
            float* __restrict__ bMf, float* __restrict__ bAf,
            float* __restrict__ b1f, float* __restrict__ W2f,
            float* __restrict__ b2f) {
    const int isbf = probe_isbf((const u16*)x);
    int t = blockIdx.x * 256 + threadIdx.x;
    if (t < F_CAT * K_PAD) {
        int n = t / K_PAD, k = t - n * K_PAD;
        u16 v = 0;
        if (k < F_IN) {
            const void* W = (n < 48) ? WM : (n < 96) ? WA : WS;
            int nn = (n < 48) ? n : (n < 96) ? n - 48 : n - 96;
            if (isbf) v = ((const u16*)W)[(size_t)k * 48 + nn];
            else      v = f2bf(((const float*)W)[(size_t)k * 48 + nn]);
        }
        Wt[(size_t)n * K_PAD + k] = v;
        return;
    }
    t -= F_CAT * K_PAD;
    if (t < F_MID * K_MLP) {       // W1bt[j][k] = bf16(W1[k][j]), zero-pad k>=144
        int j = t / K_MLP, k = t - j * K_MLP;
        u16 v = 0;
        if (k < F_CAT) {
            if (isbf) v = ((const u16*)W1)[(size_t)k * F_MID + j];
            else      v = f2bf(((const float*)W1)[(size_t)k * F_MID + j]);
        }
        W1bt[t] = v;
        return;
    }
    t -= F_MID * K_MLP;
    if (t < 48)            { bMf[t] = ldf(bM, t, isbf); return; }
    t -= 48;
    if (t < 48)            { bAf[t] = ldf(bA, t, isbf); return; }
    t -= 48;
    if (t < 64)            { b1f[t] = ldf(b1, t, isbf); return; }
    t -= 64;
    if (t < 64)            { W2f[t] = ldf(W2, t, isbf); return; }
    t -= 64;
    if (t < 1)             { b2f[0] = ldf(b2, 0, isbf); return; }
}

// ---------- fused front: MFMA feature GEMM + partitioned atomic histogram ---
// blocks [0, GEMM_BLOCKS): H = x @ [WM|WA|WS]  (hMB bf16 + hFull cols 96..143)
// blocks [GEMM_BLOCKS, +EPASS_BLOCKS): rank[e] = count8[col][blk&7]++
__global__ __launch_bounds__(256)
void k_front(const void* __restrict__ x, const u16* __restrict__ Wt,
             u16* __restrict__ hMB, u16* __restrict__ hFull,
             const void* __restrict__ bS, const int* __restrict__ ei,
             u32* __restrict__ count8, int* __restrict__ rank) {
    if (blockIdx.x >= GEMM_BLOCKS) {
        // -------- epass1: partitioned histogram (contention /8) --------
        const int b = blockIdx.x - GEMM_BLOCKS;
        const int e = b * 256 + threadIdx.x;
        if (e >= N_EDGES) return;
        const int is64 = probe_is64(ei);
        const int p = b & 7;
        int c = ld_col(ei, e, is64);
        rank[e] = (int)atomicAdd(&count8[(size_t)c * 8 + p], 1u);
        return;
    }
    // -------- gemm --------
    const int isbf = probe_isbf((const u16*)x);
    const int lane = threadIdx.x & 63;
    const int wave = threadIdx.x >> 6;
    const int mrow = lane & 15;
    const int q    = lane >> 4;
    const int m_base = blockIdx.x * 128 + wave * 32;

    floatx4 acc[2][9];
#pragma unroll
    for (int tt = 0; tt < 2; ++tt)
#pragma unroll
        for (int t = 0; t < 9; ++t) {
            acc[tt][t][0]=0.f; acc[tt][t][1]=0.f; acc[tt][t][2]=0.f; acc[tt][t][3]=0.f;
        }

    for (int k0 = 0; k0 < K_PAD; k0 += 32) {
        int k = k0 + q * 8;
        short8 a[2];
#pragma unroll
        for (int tt = 0; tt < 2; ++tt) {
            int node = m_base + tt * 16 + mrow;
            short8 av = {0,0,0,0,0,0,0,0};
            if (node < N_NODES && k < F_IN) {
                if (isbf) {
                    av = *(const short8*)((const u16*)x + (size_t)node * F_IN + k);
                } else {
                    const float* xf = (const float*)x + (size_t)node * F_IN + k;
                    floatx4 v0 = *(const floatx4*)xf;
                    floatx4 v1 = *(const floatx4*)(xf + 4);
                    av[0]=(short)f2bf(v0[0]); av[1]=(short)f2bf(v0[1]);
                    av[2]=(short)f2bf(v0[2]); av[3]=(short)f2bf(v0[3]);
                    av[4]=(short)f2bf(v1[0]); av[5]=(short)f2bf(v1[1]);
                    av[6]=(short)f2bf(v1[2]); av[7]=(short)f2bf(v1[3]);
                }
            }
            a[tt] = av;
        }
#pragma unroll
        for (int t = 0; t < 9; ++t) {
            short8 b = *(const short8*)(Wt + (size_t)(t * 16 + mrow) * K_PAD + k);
            acc[0][t] = __builtin_amdgcn_mfma_f32_16x16x32_bf16(a[0], b, acc[0][t], 0, 0, 0);
            acc[1][t] = __builtin_amdgcn_mfma_f32_16x16x32_bf16(a[1], b, acc[1][t], 0, 0, 0);
        }
    }
#pragma unroll
    for (int tt = 0; tt < 2; ++tt)
#pragma unroll
    for (int t = 0; t < 9; ++t) {
        int n = t * 16 + mrow;                      // C/D col = lane&15
#pragma unroll
        for (int r = 0; r < 4; ++r) {
            int row = m_base + tt * 16 + q * 4 + r; // C/D row = (lane>>4)*4 + reg
            if (row < N_NODES) {
                float v = acc[tt][t][r];
                if (n < 96) hMB[(size_t)row * 96 + n] = f2bf(v);
                else        hFull[(size_t)row * F_CAT + n] =
                                f2bf(fmaxf(v + ldf(bS, n - 96, isbf), 0.f));
            }
        }
    }
}

__global__ __launch_bounds__(1024)
void k_scan(const u32* __restrict__ count8, int* __restrict__ rowptr) {
    __shared__ int part[1024];
    const int tid = threadIdx.x;
    const int CH = 52;                 // 1024*52 = 53248 >= 50000
    int base = tid * CH;
    int s = 0;
    for (int i = 0; i < CH; ++i) {
        int idx = base + i;
        if (idx < N_NODES) {
            const uint4* c8 = (const uint4*)(count8 + (size_t)idx * 8);
            uint4 a = c8[0], b = c8[1];
            s += (int)(a.x + a.y + a.z + a.w + b.x + b.y + b.z + b.w);
        }
    }
    part[tid] = s;
    __syncthreads();
    for (int off = 1; off < 1024; off <<= 1) {
        int v = (tid >= off) ? part[tid - off] : 0;
        __syncthreads();
        part[tid] += v;
        __syncthreads();
    }
    int run = part[tid] - s;           // exclusive prefix of this chunk
    for (int i = 0; i < CH; ++i) {
        int idx = base + i;
        if (idx < N_NODES) {
            const uint4* c8 = (const uint4*)(count8 + (size_t)idx * 8);
            uint4 a = c8[0], b = c8[1];
            int tot = (int)(a.x + a.y + a.z + a.w + b.x + b.y + b.z + b.w);
            rowptr[idx] = run; run += tot;
        }
    }
    if (tid == 1023) rowptr[N_NODES] = part[1023];
}

// pass 2: atomic-free placement — slot = rowptr[c] + partition prefix + rank
__global__ __launch_bounds__(256)
void k_epass2(const void* __restrict__ x, const int* __restrict__ ei,
              const void* __restrict__ ew, const int* __restrict__ rowptr,
              const int* __restrict__ rank, const u32* __restrict__ count8,
              int2* __restrict__ csr_pair) {
    int e = blockIdx.x * 256 + threadIdx.x;
    if (e >= N_EDGES) return;
    const int isbf = probe_isbf((const u16*)x);
    const int is64 = probe_is64(ei);
    int r = ld_row(ei, e, is64);
    int c = ld_col(ei, e, is64);
    float w = ldf(ew, e, isbf);
    int p = (e >> 8) & 7;              // epass1 block = e/256, partition = blk&7
    const uint4* c8 = (const uint4*)(count8 + (size_t)c * 8);
    uint4 A = c8[0], B = c8[1];
    int pre = 0;
    u32 v[8] = {A.x, A.y, A.z, A.w, B.x, B.y, B.z, B.w};
#pragma unroll
    for (int q = 0; q < 7; ++q) pre += (q < p) ? (int)v[q] : 0;
    int slot = rowptr[c] + pre + rank[e];
    csr_pair[slot] = make_int2(r, __float_as_int(w));
}

// deg/dis from CSR segments, no atomics: one wave per node
__global__ __launch_bounds__(256)
void k_deg(const int* __restrict__ rowptr, const int2* __restrict__ csr_pair,
           float* __restrict__ dis) {
    const int lane = threadIdx.x & 63;
    const int node = blockIdx.x * 4 + (threadIdx.x >> 6);
    int start = rowptr[node], end = rowptr[node + 1];
    float s = 0.f;
    for (int i = start + lane; i < end; i += 64)
        s += __int_as_float(csr_pair[i].y);
#pragma unroll
    for (int off = 32; off > 0; off >>= 1) s += __shfl_down(s, off, 64);
    if (lane == 0) dis[node] = rsqrtf(1.0f + s);   // +1 = self-loop
}

// ---------- aggregation only: one wave per node, writes hFull[.][0..95] ------
__global__ __launch_bounds__(256)
void k_agg(const u16* __restrict__ hMB, u16* __restrict__ hFull,
           const int* __restrict__ rowptr, const int2* __restrict__ csr_pair,
           const float* __restrict__ dis,
           const float* __restrict__ bMf, const float* __restrict__ bAf) {
    const int lane = threadIdx.x & 63;
    const int wave = threadIdx.x >> 6;
    const int node = blockIdx.x * 4 + wave;   // grid = 12500*4 == 50000 exactly

    const int g = lane / 12;                  // edge group 0..5 (g==5: lanes 60-63 pad)
    const int s = lane - g * 12;              // feature slot 0..11 (8 bf16 each)
    const bool active = lane < 60;
    const bool isMax = s < 6;                 // slots 0..5: hM max, 6..11: hA sum

    const int start = rowptr[node];
    const int end   = rowptr[node + 1];
    const float dn  = dis[node];
    const float dn2 = dn * dn;                // self-loop norm

    const u16* nrow = hMB + (size_t)node * 96 + 8 * s;

    // seed with self-loop (max lanes every group — idempotent; sum only g==0)
    floatx4 a0, a1;
    {
        short8 rv = *(const short8*)nrow;
        float seed = (isMax || g == 0) ? dn2 : 0.f;
#pragma unroll
        for (int j = 0; j < 4; ++j) {
            a0[j] = seed * bf2f((u16)rv[j]);
            a1[j] = seed * bf2f((u16)rv[4 + j]);
        }
    }

    for (int c0 = start; c0 < end; c0 += 64) {
        int cl = end - c0; if (cl > 64) cl = 64;
        int li = lane < cl ? lane : cl - 1;
        int2 mp = csr_pair[c0 + li];
        float mynm = __int_as_float(mp.y) * dis[mp.x] * dn;   // full norm

        for (int j = 0; j < cl; j += 20) {
            const u16* rp[4]; float nmv[4];
#pragma unroll
            for (int u = 0; u < 4; ++u) {
                int el = j + 5 * u + g;
                bool valid = active && (el < cl);
                int elc = (el < cl) ? el : 0;
                int r    = __shfl(mp.x, elc, 64);
                float nm = __shfl(mynm, elc, 64);
                if (!valid) { nm = isMax ? dn2 : 0.f; }
                rp[u]  = valid ? (hMB + (size_t)r * 96 + 8 * s) : nrow;
                nmv[u] = nm;
            }
            short8 rv[4];
#pragma unroll
            for (int u = 0; u < 4; ++u) rv[u] = *(const short8*)rp[u];
#pragma unroll
            for (int u = 0; u < 4; ++u) {
                floatx4 m0, m1;
#pragma unroll
                for (int jj = 0; jj < 4; ++jj) {
                    m0[jj] = nmv[u] * bf2f((u16)rv[u][jj]);
                    m1[jj] = nmv[u] * bf2f((u16)rv[u][4 + jj]);
                }
                if (isMax) { a0 = max4(a0, m0); a1 = max4(a1, m1); }
                else       { a0 += m0;          a1 += m1; }
            }
        }
    }

#pragma unroll
    for (int gg = 1; gg < 5; ++gg) {
        int src = lane + 12 * gg;
        floatx4 t0, t1;
#pragma unroll
        for (int j = 0; j < 4; ++j) {
            t0[j] = __shfl(a0[j], src, 64);
            t1[j] = __shfl(a1[j], src, 64);
        }
        if (lane < 12) {
            if (isMax) { a0 = max4(a0, t0); a1 = max4(a1, t1); }
            else       { a0 += t0;          a1 += t1; }
        }
    }

    if (lane < 12) {
        const float* bp = isMax ? (bMf + 8 * lane) : (bAf + 8 * lane - 48);
        short8 hv;
#pragma unroll
        for (int j = 0; j < 4; ++j) {
            hv[j]     = (short)f2bf(fmaxf(a0[j] + bp[j],     0.f));
            hv[4 + j] = (short)f2bf(fmaxf(a1[j] + bp[4 + j], 0.f));
        }
        *(short8*)(hFull + (size_t)node * F_CAT + 8 * lane) = hv;
    }
}

// ---------- MLP via MFMA: out = (relu(hFull@W1+b1))@W2 + b2 ----------------
__global__ __launch_bounds__(256)
void k_mlp(const void* __restrict__ x, const u16* __restrict__ hFull,
           const u16* __restrict__ W1bt, const float* __restrict__ b1f,
           const float* __restrict__ W2f, const float* __restrict__ b2f,
           void* __restrict__ out) {
    const int isbf = probe_isbf((const u16*)x);
    const int lane = threadIdx.x & 63;
    const int wave = threadIdx.x >> 6;
    const int mrow = lane & 15;
    const int q    = lane >> 4;
    const int m_base = blockIdx.x * 64 + wave * 16;
    const int node = m_base + mrow;           // A-operand row

    floatx4 acc[4];
#pragma unroll
    for (int t = 0; t < 4; ++t) { acc[t][0]=0.f; acc[t][1]=0.f; acc[t][2]=0.f; acc[t][3]=0.f; }

    for (int k0 = 0; k0 < K_MLP; k0 += 32) {
        int k = k0 + q * 8;
        short8 a = {0,0,0,0,0,0,0,0};
        if (node < N_NODES && k < F_CAT)
            a = *(const short8*)(hFull + (size_t)node * F_CAT + k);
#pragma unroll
        for (int t = 0; t < 4; ++t) {
            short8 b = *(const short8*)(W1bt + (size_t)(t * 16 + mrow) * K_MLP + k);
            acc[t] = __builtin_amdgcn_mfma_f32_16x16x32_bf16(a, b, acc[t], 0, 0, 0);
        }
    }

    float pr[4] = {0.f, 0.f, 0.f, 0.f};
#pragma unroll
    for (int t = 0; t < 4; ++t) {
        int n = t * 16 + mrow;
        float b1v = b1f[n], w2v = W2f[n];
#pragma unroll
        for (int r = 0; r < 4; ++r)
            pr[r] += fmaxf(acc[t][r] + b1v, 0.f) * w2v;
    }
#pragma unroll
    for (int mask = 1; mask < 16; mask <<= 1)
#pragma unroll
        for (int r = 0; r < 4; ++r) pr[r] += __shfl_xor(pr[r], mask, 64);
    if (mrow == 0) {
#pragma unroll
        for (int r = 0; r < 4; ++r) {
            int nd = m_base + q * 4 + r;
            if (nd < N_NODES) {
                float res = pr[r] + b2f[0];
                if (isbf) ((u16*)out)[nd] = f2bf(res);
                else      ((float*)out)[nd] = res;
            }
        }
    }
}

extern "C" void kernel_launch(void* const* d_in, const int* in_sizes, int n_in,
                              void* d_out, int out_size, void* d_ws, size_t ws_size,
                              hipStream_t stream) {
    const void* x  = d_in[0];
    const int*  ei = (const int*)d_in[1];
    const void* ew = d_in[2];
    const void* WM = d_in[3];
    const void* bM = d_in[4];
    const void* WA = d_in[5];
    const void* bA = d_in[6];
    const void* WS = d_in[7];
    const void* bS = d_in[8];
    const void* W1 = d_in[9];
    const void* b1 = d_in[10];
    const void* W2 = d_in[11];
    const void* b2 = d_in[12];

    char* p = (char*)d_ws;
    auto alloc = [&](size_t bytes) -> char* {
        char* r = p; p += (bytes + 255) & ~(size_t)255; return r;
    };
    float* dis      = (float*)alloc((size_t)N_NODES * 4);
    u32*   count8   = (u32*)  alloc((size_t)N_NODES * 8 * 4);
    int*   rowptr   = (int*)  alloc((size_t)(N_NODES + 1) * 4);
    int*   rank     = (int*)  alloc((size_t)N_EDGES * 4);
    int2*  csr_pair = (int2*) alloc((size_t)N_EDGES * 8);
    u16*   hMB      = (u16*)  alloc((size_t)N_NODES * 96 * 2);
    u16*   hFull    = (u16*)  alloc((size_t)N_NODES * F_CAT * 2);
    u16*   Wt       = (u16*)  alloc((size_t)F_CAT * K_PAD * 2);
    u16*   W1bt     = (u16*)  alloc((size_t)F_MID * K_MLP * 2);
    float* bMf      = (float*)alloc(48 * 4);
    float* bAf      = (float*)alloc(48 * 4);
    float* b1f      = (float*)alloc(64 * 4);
    float* W2f      = (float*)alloc(64 * 4);
    float* b2f      = (float*)alloc(4);

    hipMemsetAsync(count8, 0, (size_t)N_NODES * 8 * 4, stream);
    k_prep  <<<(F_CAT * K_PAD + F_MID * K_MLP + 225 + 255) / 256, 256, 0, stream>>>(
                 x, WM, WA, WS, W1, bM, bA, b1, W2, b2,
                 Wt, W1bt, bMf, bAf, b1f, W2f, b2f);
    k_front <<<GEMM_BLOCKS + EPASS_BLOCKS, 256, 0, stream>>>(
                 x, Wt, hMB, hFull, bS, ei, count8, rank);
    k_scan  <<<1, 1024, 0, stream>>>(count8, rowptr);
    k_epass2<<<EPASS_BLOCKS, 256, 0, stream>>>(x, ei, ew, rowptr, rank, count8, csr_pair);
    k_deg   <<<(N_NODES + 3) / 4, 256, 0, stream>>>(rowptr, csr_pair, dis);
    k_agg   <<<N_NODES / 4, 256, 0, stream>>>(hMB, hFull, rowptr, csr_pair, dis, bMf, bAf);
    k_mlp   <<<(N_NODES + 63) / 64, 256, 0, stream>>>(x, hFull, W1bt, b1f, W2f, b2f, d_out);
    (void)in_sizes; (void)n_in; (void)out_size; (void)ws_size;
}